// Round 4
// baseline (673.252 us; speedup 1.0000x reference)
//
#include <hip/hip_runtime.h>
#include <cmath>

#define HIDDEN 256
#define NUM_REL 6
#define KTOT 1792   // 6 relations * 256 + root block 256

typedef float f32x4_t __attribute__((ext_vector_type(4)));
typedef short bf16x8_t __attribute__((ext_vector_type(8)));

__device__ __forceinline__ float bf2f(ushort u) {
  return __uint_as_float(((uint)u) << 16);
}
__device__ __forceinline__ ushort f2bf(float f) {
  uint u = __float_as_uint(f);
  u += 0x7FFFu + ((u >> 16) & 1u);
  return (ushort)(u >> 16);
}

// ---------------- Wall[r][k][o] = sum_b att[r,b] * basis[b][k][o] -----------
__global__ void compute_W_kernel(const float* __restrict__ att,
                                 const float* __restrict__ basis,
                                 float* __restrict__ Wall) {
  int idx = blockIdx.x * blockDim.x + threadIdx.x;   // over 6*65536
  int r  = idx >> 16;
  int io = idx & 65535;
  float s = 0.f;
#pragma unroll
  for (int b = 0; b < 30; ++b)
    s += att[r * 30 + b] * basis[(size_t)b * 65536 + io];
  Wall[idx] = s;
}

// ---------------- gatevec[r][d] = sum_e Wall[r][d][e] * gate_w[e] -----------
__global__ __launch_bounds__(256) void gatevec_kernel(
    const float* __restrict__ Wall, const float* __restrict__ gw,
    float* __restrict__ gatevec) {
  const int wave = (blockIdx.x * blockDim.x + threadIdx.x) >> 6;  // 0..1535
  const int l = threadIdx.x & 63;
  const int r = wave >> 8, d = wave & 255;
  float4 wv = ((const float4*)(Wall + (size_t)r * 65536 + d * 256))[l];
  float4 gv = ((const float4*)gw)[l];
  float dot = wv.x * gv.x + wv.y * gv.y + wv.z * gv.z + wv.w * gv.w;
#pragma unroll
  for (int off = 32; off; off >>= 1) dot += __shfl_xor(dot, off);
  if (l == 0) gatevec[r * 256 + d] = dot;
}

// ---------------- BT2[o][r*256+k] = W_r[k][o] (r=6 -> root) -----------------
__global__ __launch_bounds__(256) void build_BT2(const float* __restrict__ Wall,
                                                 const float* __restrict__ root,
                                                 ushort* __restrict__ BT2) {
  __shared__ float t[64][65];
  const int o0 = blockIdx.x * 64, k0 = blockIdx.y * 64, r = blockIdx.z;
  const float* S = (r < 6) ? (Wall + (size_t)r * 65536) : root;
  const int tx = threadIdx.x & 63, ty = threadIdx.x >> 6;
  for (int kk = ty; kk < 64; kk += 4)
    t[kk][tx] = S[(size_t)(k0 + kk) * 256 + o0 + tx];
  __syncthreads();
  for (int oo = ty; oo < 64; oo += 4)
    BT2[(size_t)(o0 + oo) * KTOT + r * 256 + k0 + tx] = f2bf(t[tx][oo]);
}

// ---------------- fp32 -> bf16 convert --------------------------------------
__global__ void cvt_f32_bf16(const float* __restrict__ in,
                             ushort* __restrict__ out, int n4) {
  int i = blockIdx.x * blockDim.x + threadIdx.x;
  if (i >= n4) return;
  float4 v = ((const float4*)in)[i];
  ushort4 o;
  o.x = f2bf(v.x); o.y = f2bf(v.y); o.z = f2bf(v.z); o.w = f2bf(v.w);
  ((ushort4*)out)[i] = o;
}

// ---------------- gdot[r][n] = x[n] . gatevec[r] ----------------------------
__global__ __launch_bounds__(256) void gdot_kernel(
    const ushort* __restrict__ xb, const float* __restrict__ gatevec,
    float* __restrict__ gdotc, int N) {
  const int wave = (blockIdx.x * blockDim.x + threadIdx.x) >> 6;
  if (wave >= N) return;
  const int l = threadIdx.x & 63;
  ushort4 xv = ((const ushort4*)(xb + (size_t)wave * 256))[l];
  const float x0 = bf2f(xv.x), x1 = bf2f(xv.y), x2 = bf2f(xv.z), x3 = bf2f(xv.w);
  float out = 0.f;
#pragma unroll
  for (int r = 0; r < NUM_REL; ++r) {
    float4 gv = ((const float4*)(gatevec + r * 256))[l];
    float d = x0 * gv.x + x1 * gv.y + x2 * gv.z + x3 * gv.w;
#pragma unroll
    for (int off = 32; off; off >>= 1) d += __shfl_xor(d, off);
    if (l == r) out = d;
  }
  if (l < NUM_REL) gdotc[(size_t)l * N + wave] = out;
}

// ---------------- edge aggregation: one wave per dst node -------------------
// A[n][r*256+c] = (1/deg) * sum_{e in (r,n)} sigmoid(gdot[r][src]+gb)*x[src][c]
// A[n][1536+c]  = x[n][c]   (root block copy)
__global__ __launch_bounds__(256) void edge_agg(
    const ushort* __restrict__ xb, const float* __restrict__ gdotc,
    const float* __restrict__ gate_b, const int* __restrict__ row_ptr,
    const int* __restrict__ src_s, const float* __restrict__ deg,
    ushort* __restrict__ A, int N) {
  const int wave = (blockIdx.x * blockDim.x + threadIdx.x) >> 6;
  if (wave >= N) return;
  const int l = threadIdx.x & 63;
  const float gb = gate_b[0];
  const float inv = 1.f / fmaxf(deg[wave], 1.f);
  ushort* Arow = A + (size_t)wave * KTOT;

#pragma unroll
  for (int r = 0; r < NUM_REL; ++r) {
    const int bin = r * N + wave;
    const int e1 = row_ptr[bin + 1];
    float ax = 0.f, ay = 0.f, az = 0.f, aw = 0.f;
    const float* gd = gdotc + (size_t)r * N;
    for (int e = row_ptr[bin]; e < e1; ++e) {
      const int s = src_s[e];
      const ushort4 xv = ((const ushort4*)(xb + (size_t)s * 256))[l];
      const float g = 1.f / (1.f + __expf(-(gd[s] + gb)));
      ax += g * bf2f(xv.x); ay += g * bf2f(xv.y);
      az += g * bf2f(xv.z); aw += g * bf2f(xv.w);
    }
    ushort4 o;
    o.x = f2bf(ax * inv); o.y = f2bf(ay * inv);
    o.z = f2bf(az * inv); o.w = f2bf(aw * inv);
    ((ushort4*)(Arow + r * 256))[l] = o;
  }
  // root block: copy own x row
  ((ushort4*)(Arow + 1536))[l] = ((const ushort4*)(xb + (size_t)wave * 256))[l];
}

// ---------------- bf16 MFMA GEMM + fused epilogue ---------------------------
// out[M,256] = A[M,1792] @ BT2[256,1792]^T + bias; mode 0: relu+bf16 out,
// mode 1: f32 out.
__global__ __launch_bounds__(256) void gemm_fused(const ushort* __restrict__ A,
                                                  const ushort* __restrict__ BT,
                                                  const float* __restrict__ bias,
                                                  void* __restrict__ outPtr,
                                                  int M, int mode) {
  __shared__ ushort As[128 * 64];
  __shared__ ushort Bs[128 * 64];
  const int tid = threadIdx.x;
  const int w = tid >> 6, l = tid & 63;
  const int wm = w & 1, wn = w >> 1;
  const int row0 = blockIdx.x * 128;
  const int col0 = blockIdx.y * 128;

  const int srow = l >> 3;
  const int schunk = (l & 7) ^ srow;

  f32x4_t acc[4][4] = {};

  for (int k0 = 0; k0 < KTOT; k0 += 64) {
    if (k0) __syncthreads();
#pragma unroll
    for (int i = 0; i < 4; ++i) {
      const int br = (w * 4 + i) * 8;
      const int ga = min(row0 + br + srow, M - 1);
      const ushort* gp = A + (size_t)ga * KTOT + k0 + schunk * 8;
      __builtin_amdgcn_global_load_lds(
          (const __attribute__((address_space(1))) void*)gp,
          (__attribute__((address_space(3))) void*)(As + br * 64), 16, 0, 0);
    }
#pragma unroll
    for (int i = 0; i < 4; ++i) {
      const int br = (w * 4 + i) * 8;
      const int gb = col0 + br + srow;          // 0..255 rows of BT2
      const ushort* gp = BT + (size_t)gb * KTOT + k0 + schunk * 8;
      __builtin_amdgcn_global_load_lds(
          (const __attribute__((address_space(1))) void*)gp,
          (__attribute__((address_space(3))) void*)(Bs + br * 64), 16, 0, 0);
    }
    __syncthreads();
#pragma unroll
    for (int kk = 0; kk < 2; ++kk) {
      const int swc = (kk * 4 + (l >> 4)) ^ (l & 7);
      bf16x8_t a[4], b[4];
#pragma unroll
      for (int m = 0; m < 4; ++m) {
        const int r = wm * 64 + m * 16 + (l & 15);
        a[m] = *(const bf16x8_t*)(As + r * 64 + swc * 8);
      }
#pragma unroll
      for (int n = 0; n < 4; ++n) {
        const int r = wn * 64 + n * 16 + (l & 15);
        b[n] = *(const bf16x8_t*)(Bs + r * 64 + swc * 8);
      }
#pragma unroll
      for (int m = 0; m < 4; ++m)
#pragma unroll
        for (int n = 0; n < 4; ++n)
          acc[m][n] = __builtin_amdgcn_mfma_f32_16x16x32_bf16(
              a[m], b[n], acc[m][n], 0, 0, 0);
    }
  }

  const int rbase = row0 + wm * 64 + (l >> 4) * 4;
  const int cbase = col0 + wn * 64 + (l & 15);
#pragma unroll
  for (int n = 0; n < 4; ++n) {
    const int col = cbase + n * 16;
    const float bv = bias[col];
#pragma unroll
    for (int m = 0; m < 4; ++m)
#pragma unroll
      for (int i = 0; i < 4; ++i) {
        const int row = rbase + m * 16 + i;
        if (row < M) {
          float v = acc[m][n][i] + bv;
          if (mode == 0) {
            v = fmaxf(v, 0.f);
            ((ushort*)outPtr)[(size_t)row * 256 + col] = f2bf(v);
          } else {
            ((float*)outPtr)[(size_t)row * 256 + col] = v;
          }
        }
      }
  }
}

// ---------------- CSR build -------------------------------------------------
__global__ void hist_kernel(const int* __restrict__ dst,
                            const int* __restrict__ ety,
                            int* __restrict__ cnt, int E, int N) {
  int stride = gridDim.x * blockDim.x;
  for (int e = blockIdx.x * blockDim.x + threadIdx.x; e < E; e += stride)
    atomicAdd(&cnt[ety[e] * N + dst[e]], 1);
}

__global__ void scan_reduce(const int* __restrict__ cnt,
                            int* __restrict__ blockSums, int n) {
  __shared__ int sd[256];
  int base = blockIdx.x * 1024;
  int t = threadIdx.x;
  int s = 0;
#pragma unroll
  for (int i = 0; i < 4; ++i) {
    int idx = base + t * 4 + i;
    s += (idx < n) ? cnt[idx] : 0;
  }
  sd[t] = s; __syncthreads();
  for (int off = 128; off; off >>= 1) {
    if (t < off) sd[t] += sd[t + off];
    __syncthreads();
  }
  if (t == 0) blockSums[blockIdx.x] = sd[0];
}

__global__ void scan_offsets(int* __restrict__ blockSums, int nb) {
  if (threadIdx.x == 0 && blockIdx.x == 0) {
    int run = 0;
    for (int i = 0; i < nb; ++i) { int v = blockSums[i]; blockSums[i] = run; run += v; }
  }
}

__global__ void scan_write(const int* __restrict__ cnt,
                           const int* __restrict__ blockSums,
                           int* __restrict__ row_ptr, int n) {
  __shared__ int sd[256];
  int base = blockIdx.x * 1024;
  int t = threadIdx.x;
  int v[4]; int s = 0;
#pragma unroll
  for (int i = 0; i < 4; ++i) {
    int idx = base + t * 4 + i;
    v[i] = (idx < n) ? cnt[idx] : 0;
    s += v[i];
  }
  sd[t] = s; __syncthreads();
  for (int off = 1; off < 256; off <<= 1) {
    int val = (t >= off) ? sd[t - off] : 0;
    __syncthreads();
    sd[t] += val;
    __syncthreads();
  }
  int excl = blockSums[blockIdx.x] + sd[t] - s;
  for (int i = 0; i < 4; ++i) {
    int idx = base + t * 4 + i;
    if (idx < n) {
      row_ptr[idx] = excl;
      excl += v[i];
      if (idx == n - 1) row_ptr[n] = excl;
    }
  }
}

__global__ void scatter_kernel(const int* __restrict__ src,
                               const int* __restrict__ dst,
                               const int* __restrict__ ety,
                               int* __restrict__ cursor,
                               int* __restrict__ src_s, int E, int N) {
  int stride = gridDim.x * blockDim.x;
  for (int e = blockIdx.x * blockDim.x + threadIdx.x; e < E; e += stride) {
    int bin = ety[e] * N + dst[e];
    int pos = atomicAdd(&cursor[bin], 1);
    src_s[pos] = src[e];
  }
}

__global__ void deg_from_csr(const int* __restrict__ row_ptr,
                             float* __restrict__ deg, int N) {
  int n = blockIdx.x * blockDim.x + threadIdx.x;
  if (n >= N) return;
  int d = 0;
#pragma unroll
  for (int r = 0; r < NUM_REL; ++r)
    d += row_ptr[r * N + n + 1] - row_ptr[r * N + n];
  deg[n] = (float)d;
}

static inline size_t align16(size_t x) { return (x + 15) & ~(size_t)15; }

extern "C" void kernel_launch(void* const* d_in, const int* in_sizes, int n_in,
                              void* d_out, int out_size, void* d_ws,
                              size_t ws_size, hipStream_t stream) {
  const float* x    = (const float*)d_in[0];
  const int*   src  = (const int*)d_in[1];
  const int*   dst  = (const int*)d_in[2];
  const int*   ety  = (const int*)d_in[3];

  const int N  = in_sizes[0] / HIDDEN;   // 50000
  const int E  = in_sizes[1];            // 800000
  const int RN = NUM_REL * N;

  // ---- workspace layout ----
  char* p = (char*)d_ws;
  float* Wall    = (float*)p;  p += align16((size_t)NUM_REL * 65536 * 4);
  ushort* BT2    = (ushort*)p; p += align16((size_t)256 * KTOT * 2);
  float* gatevec = (float*)p;  p += align16((size_t)NUM_REL * 256 * 4);
  float* gdotc   = (float*)p;  p += align16((size_t)RN * 4);
  ushort* xb     = (ushort*)p; p += align16((size_t)N * HIDDEN * 2);
  float* deg     = (float*)p;  p += align16((size_t)N * 4);
  int* cnt       = (int*)p;    p += align16((size_t)RN * 4);
  int* cursor    = (int*)p;    p += align16((size_t)RN * 4);
  int* row_ptr   = (int*)p;    p += align16((size_t)(RN + 1) * 4);
  int* blockSums = (int*)p;    p += 2048;
  int* src_s     = (int*)p;    p += align16((size_t)E * 4);
  ushort* A      = (ushort*)p;   // N * KTOT bf16 = 179 MB

  const int scanBlocks = (RN + 1023) / 1024;

  // ---- CSR build (shared by both layers) ----
  hipMemsetAsync(cnt, 0, (size_t)RN * sizeof(int), stream);
  hist_kernel<<<2048, 256, 0, stream>>>(dst, ety, cnt, E, N);
  scan_reduce<<<scanBlocks, 256, 0, stream>>>(cnt, blockSums, RN);
  scan_offsets<<<1, 64, 0, stream>>>(blockSums, scanBlocks);
  scan_write<<<scanBlocks, 256, 0, stream>>>(cnt, blockSums, row_ptr, RN);
  hipMemcpyAsync(cursor, row_ptr, (size_t)RN * sizeof(int),
                 hipMemcpyDeviceToDevice, stream);
  scatter_kernel<<<2048, 256, 0, stream>>>(src, dst, ety, cursor, src_s, E, N);
  deg_from_csr<<<(N + 255) / 256, 256, 0, stream>>>(row_ptr, deg, N);

  // x -> bf16
  cvt_f32_bf16<<<(N * 64 + 255) / 256, 256, 0, stream>>>(x, xb, N * 64);

  const int nodeBlocks = (N * 64 + 255) / 256;   // wave-per-node launches
  const int mBlocks = (N + 127) / 128;

  for (int layer = 0; layer < 2; ++layer) {
    const float* bas  = (const float*)d_in[layer ? 10 : 4];
    const float* att  = (const float*)d_in[layer ? 11 : 5];
    const float* root = (const float*)d_in[layer ? 12 : 6];
    const float* bias = (const float*)d_in[layer ? 13 : 7];
    const float* gw   = (const float*)d_in[layer ? 14 : 8];
    const float* gb   = (const float*)d_in[layer ? 15 : 9];
    void* outp = layer ? d_out : (void*)xb;   // layer0: h (bf16) in place
    const int mode = layer ? 1 : 0;

    compute_W_kernel<<<NUM_REL * 65536 / 256, 256, 0, stream>>>(att, bas, Wall);
    gatevec_kernel<<<384, 256, 0, stream>>>(Wall, gw, gatevec);
    build_BT2<<<dim3(4, 4, 7), 256, 0, stream>>>(Wall, root, BT2);
    gdot_kernel<<<nodeBlocks, 256, 0, stream>>>(xb, gatevec, gdotc, N);
    edge_agg<<<nodeBlocks, 256, 0, stream>>>(xb, gdotc, gb, row_ptr, src_s,
                                             deg, A, N);
    gemm_fused<<<dim3(mBlocks, 2), 256, 0, stream>>>(A, BT2, bias, outp, N,
                                                     mode);
  }
}